// Round 14
// baseline (207.540 us; speedup 1.0000x reference)
//
#include <hip/hip_runtime.h>
#include <hip/hip_bf16.h>

#define N_NODES 50000
#define DIM 128
#define N_EDGES 625000
#define EBLK 2442  // ceil(E/256) edge blocks, 1 edge/thread
#define SLOTS 96   // fixed CSR slots/node; deg ~ Binom(625k,1/50k): P(>96) ~ 1e-90
#define CSTRIDE 16 // cnt padded: 1 counter per 64B line (kills XCD line bouncing)

// fused setup+bucket grid: scale (25000) + pack (256) interleaved with bucket (2442)
#define SC_BLOCKS 25000           // 8 rows/block over 4N rows
#define PK_BLOCKS 256             // W-pack: 65536 elems
#define OT_BLOCKS (SC_BLOCKS + PK_BLOCKS)   // 25256 "other" blocks
#define IL_SPAN (EBLK * 11)       // 26862: interleave span (1 bucket per 11)
#define SB_BLOCKS (OT_BLOCKS + EBLK)        // 27698 total

typedef float f32x4 __attribute__((ext_vector_type(4)));
typedef short s16x8 __attribute__((ext_vector_type(8)));

__device__ __forceinline__ unsigned short f2bf(float f) {
    unsigned u = __builtin_bit_cast(unsigned, f);
    unsigned r = (u + 0x7fffu + ((u >> 16) & 1u)) >> 16;  // RNE
    return (unsigned short)r;
}
__device__ __forceinline__ unsigned cvtpk_bf16(float lo, float hi) {
    // v_cvt_pk_bf16_f32 via intrinsic; union pun (bit_cast rejects bf162)
    union { __hip_bfloat162 h; unsigned u; } cv;
    cv.h = __float22bfloat162_rn(make_float2(lo, hi));
    return cv.u;
}
__device__ __forceinline__ float lo_bf(unsigned u) {
    return __builtin_bit_cast(float, u << 16);
}
__device__ __forceinline__ float hi_bf(unsigned u) {
    return __builtin_bit_cast(float, u & 0xffff0000u);
}

// async global->LDS, 16 B per lane; lds dest = uniform base + lane*16 (m104)
__device__ __forceinline__ void gload_lds16(const unsigned short* g, unsigned short* l) {
    __builtin_amdgcn_global_load_lds(
        (const __attribute__((address_space(1))) void*)g,
        (__attribute__((address_space(3))) void*)l, 16, 0, 0);
}

// logmap0 scale factor for one row given sum-of-squares reduced across group
__device__ __forceinline__ float logmap_scale(float ss, float sc) {
    float xn = fmaxf(sqrtf(ss), 1e-15f);
    float arg = fminf(sc * xn, 1.0f - 1e-5f);
    // s = artanh(arg)/(sc*xn); for arg<0.25 the clip is inactive so the
    // division cancels: artanh(z)/z = 1 + z^2/3 + z^4/5 + z^6/7 (rel err ~2e-6)
    if (arg < 0.25f) {
        float z2 = arg * arg;
        return 1.0f + z2 * (0.33333333f + z2 * (0.2f + z2 * 0.14285715f));
    }
    float at = 0.5f * log1pf(2.0f * arg / (1.0f - arg));
    return at / (sc * xn);
}

// ---- K1: fused setup + pack + INTERLEAVED bucket (R11-measured: 50us,
// bucket hides under setup; serial tail-fusion was 63) -- FROZEN ----
__global__ __launch_bounds__(256) void k_sb(
    const float* __restrict__ node, const float* __restrict__ h1,
    const float* __restrict__ h2, const float* __restrict__ h3,
    const float* __restrict__ lin_w, const float* __restrict__ conv_w,
    const float* __restrict__ curv,
    const int* __restrict__ esrc, const int* __restrict__ edst,
    unsigned short* __restrict__ node_t, unsigned short* __restrict__ A,
    unsigned short* __restrict__ Wt, int* __restrict__ cnt,
    unsigned short* __restrict__ slots) {
    int b = blockIdx.x;
    int tid = threadIdx.x;
    int ot;
    if (b < IL_SPAN) {
        int q = b / 11;
        int r = b - q * 11;
        if (r == 5) {  // ---- bucket block: 1 edge/thread, padded counters ----
            int e = q * 256 + tid;
            if (e < N_EDGES) {
                int d = edst[e];
                int pos = __hip_atomic_fetch_add(&cnt[d * CSTRIDE], 1,
                                                 __ATOMIC_RELAXED,
                                                 __HIP_MEMORY_SCOPE_AGENT);
                if (pos < SLOTS) slots[d * SLOTS + pos] = (unsigned short)esrc[e];
            }
            return;
        }
        ot = q * 10 + (r < 5 ? r : r - 1);
    } else {
        ot = 24420 + (b - IL_SPAN);
    }
    if (ot < SC_BLOCKS) {
        // ---- scale: 32 lanes/row, one float4/lane = dense 1KB loads ----
        int row = ot * 8 + (tid >> 5);  // [0, 4N); row uniform per 32-lane group
        int g = tid & 31;               // float4 index within the 128-float row
        int a = row / N_NODES;
        int n = row - a * N_NODES;
        const float* src = (a == 0) ? node : (a == 1) ? h1 : (a == 2) ? h2 : h3;
        float4 x = ((const float4*)&src[n * DIM])[g];
        float ss = x.x * x.x + x.y * x.y + x.z * x.z + x.w * x.w;
        ss += __shfl_xor(ss, 1, 64);
        ss += __shfl_xor(ss, 2, 64);
        ss += __shfl_xor(ss, 4, 64);
        ss += __shfl_xor(ss, 8, 64);
        ss += __shfl_xor(ss, 16, 64);  // 32-lane group reduction
        float c = fabsf(curv[0]);
        float s = logmap_scale(ss, sqrtf(c));
        uint2 ov;
        ov.x = cvtpk_bf16(x.x * s, x.y * s);
        ov.y = cvtpk_bf16(x.z * s, x.w * s);
        if (a == 0) {  // uniform per 32-lane group
            *(uint2*)&node_t[n * DIM + g * 4] = ov;
        } else {
            *(uint2*)&A[n * 512 + a * 128 + g * 4] = ov;
        }
    } else {
        // ---- pack Wt ----
        int idx = (ot - SC_BLOCKS) * 256 + tid;  // 65536
        int o = idx >> 9;
        int k = idx & 511;
        float v;
        if (k < 128) {
            v = lin_w[o * 128 + k];
        } else {
            int kk = (k - 128) >> 7;
            int i = (k - 128) & 127;
            v = conv_w[o * 384 + i * 3 + kk];
        }
        Wt[idx] = f2bf(v);
    }
}

// ---- K2: gather (FROZEN from R12): 16 lanes/node, uint4 per lane ----
__global__ __launch_bounds__(256) void k_gather(
    const unsigned short* __restrict__ slots, const int* __restrict__ cnt,
    const unsigned short* __restrict__ node_t, unsigned short* __restrict__ A) {
    int n = blockIdx.x * 16 + (threadIdx.x >> 4);  // 16 nodes/block
    int lane = threadIdx.x & 15;                   // cols [8*lane, 8*lane+8)
    int ctrue = cnt[n * CSTRIDE];
    int c = ctrue < SLOTS ? ctrue : SLOTS;
    const unsigned short* row = &slots[n * SLOTS];
    float p0 = 0.f, p1 = 0.f, p2 = 0.f, p3 = 0.f;   // even-slot partials
    float p4 = 0.f, p5 = 0.f, p6 = 0.f, p7 = 0.f;
    float q0 = 0.f, q1 = 0.f, q2 = 0.f, q3 = 0.f;   // odd-slot partials
    float q4 = 0.f, q5 = 0.f, q6 = 0.f, q7 = 0.f;
    for (int base = 0; base < c; base += 16) {
        int rem = c - base;
        int m = rem < 16 ? rem : 16;
        int my = (int)row[base + (lane < m ? lane : m - 1)];
        for (int i = 0; i < m; i += 8) {
            // masked parallel batch of 8: all loads issued (clamped index),
            // out-of-range contributions predicated to 0.
            int i1 = i + 1 < m ? i + 1 : m - 1;
            int i2 = i + 2 < m ? i + 2 : m - 1;
            int i3 = i + 3 < m ? i + 3 : m - 1;
            int i4 = i + 4 < m ? i + 4 : m - 1;
            int i5 = i + 5 < m ? i + 5 : m - 1;
            int i6 = i + 6 < m ? i + 6 : m - 1;
            int i7 = i + 7 < m ? i + 7 : m - 1;
            int s0 = __shfl(my, i, 16),  s1 = __shfl(my, i1, 16);
            int s2 = __shfl(my, i2, 16), s3 = __shfl(my, i3, 16);
            int s4 = __shfl(my, i4, 16), s5 = __shfl(my, i5, 16);
            int s6 = __shfl(my, i6, 16), s7 = __shfl(my, i7, 16);
            uint4 u0 = *(const uint4*)&node_t[s0 * DIM + lane * 8];
            uint4 u1 = *(const uint4*)&node_t[s1 * DIM + lane * 8];
            uint4 u2 = *(const uint4*)&node_t[s2 * DIM + lane * 8];
            uint4 u3 = *(const uint4*)&node_t[s3 * DIM + lane * 8];
            uint4 u4 = *(const uint4*)&node_t[s4 * DIM + lane * 8];
            uint4 u5 = *(const uint4*)&node_t[s5 * DIM + lane * 8];
            uint4 u6 = *(const uint4*)&node_t[s6 * DIM + lane * 8];
            uint4 u7 = *(const uint4*)&node_t[s7 * DIM + lane * 8];
            p0 += lo_bf(u0.x); p1 += hi_bf(u0.x); p2 += lo_bf(u0.y); p3 += hi_bf(u0.y);
            p4 += lo_bf(u0.z); p5 += hi_bf(u0.z); p6 += lo_bf(u0.w); p7 += hi_bf(u0.w);
            if (i + 1 < m) {
                q0 += lo_bf(u1.x); q1 += hi_bf(u1.x); q2 += lo_bf(u1.y); q3 += hi_bf(u1.y);
                q4 += lo_bf(u1.z); q5 += hi_bf(u1.z); q6 += lo_bf(u1.w); q7 += hi_bf(u1.w);
            }
            if (i + 2 < m) {
                p0 += lo_bf(u2.x); p1 += hi_bf(u2.x); p2 += lo_bf(u2.y); p3 += hi_bf(u2.y);
                p4 += lo_bf(u2.z); p5 += hi_bf(u2.z); p6 += lo_bf(u2.w); p7 += hi_bf(u2.w);
            }
            if (i + 3 < m) {
                q0 += lo_bf(u3.x); q1 += hi_bf(u3.x); q2 += lo_bf(u3.y); q3 += hi_bf(u3.y);
                q4 += lo_bf(u3.z); q5 += hi_bf(u3.z); q6 += lo_bf(u3.w); q7 += hi_bf(u3.w);
            }
            if (i + 4 < m) {
                p0 += lo_bf(u4.x); p1 += hi_bf(u4.x); p2 += lo_bf(u4.y); p3 += hi_bf(u4.y);
                p4 += lo_bf(u4.z); p5 += hi_bf(u4.z); p6 += lo_bf(u4.w); p7 += hi_bf(u4.w);
            }
            if (i + 5 < m) {
                q0 += lo_bf(u5.x); q1 += hi_bf(u5.x); q2 += lo_bf(u5.y); q3 += hi_bf(u5.y);
                q4 += lo_bf(u5.z); q5 += hi_bf(u5.z); q6 += lo_bf(u5.w); q7 += hi_bf(u5.w);
            }
            if (i + 6 < m) {
                p0 += lo_bf(u6.x); p1 += hi_bf(u6.x); p2 += lo_bf(u6.y); p3 += hi_bf(u6.y);
                p4 += lo_bf(u6.z); p5 += hi_bf(u6.z); p6 += lo_bf(u6.w); p7 += hi_bf(u6.w);
            }
            if (i + 7 < m) {
                q0 += lo_bf(u7.x); q1 += hi_bf(u7.x); q2 += lo_bf(u7.y); q3 += hi_bf(u7.y);
                q4 += lo_bf(u7.z); q5 += hi_bf(u7.z); q6 += lo_bf(u7.w); q7 += hi_bf(u7.w);
            }
        }
    }
    float inv = (ctrue > 0) ? 1.0f / (float)ctrue : 0.0f;
    uint4 ov;
    ov.x = cvtpk_bf16((p0 + q0) * inv, (p1 + q1) * inv);
    ov.y = cvtpk_bf16((p2 + q2) * inv, (p3 + q3) * inv);
    ov.z = cvtpk_bf16((p4 + q4) * inv, (p5 + q5) * inv);
    ov.w = cvtpk_bf16((p6 + q6) * inv, (p7 + q7) * inv);
    *(uint4*)&A[n * 512 + lane * 8] = ov;
}

// ---- K3: [N x 512] @ [512 x 128] bf16 MFMA GEMM + expmap0 epilogue ----
// T4 pipeline (guide m218): 3 LDS buffers, 2-chunks-ahead prefetch, COUNTED
// s_waitcnt vmcnt(4) + raw s_barrier -- the prefetched loads stay in flight
// ACROSS the barrier instead of being drained to vmcnt(0) by __syncthreads.
// Each stage gets 2 full iterations (~2 barriers + 2 MFMA phases) to land.
// Hazards: buf[(kk+2)%3] overwritten at iter kk was last read at iter kk-1,
// protected by that iteration's post-MFMA barrier. BK=32, 16 chunks,
// 48 KB LDS -> 3 blocks/CU at 512T.
#define RB 128
#define BK 32
__global__ __launch_bounds__(512) void k_gemm(
    const unsigned short* __restrict__ A, const int* __restrict__ deg,  // deg stride CSTRIDE
    const unsigned short* __restrict__ Wt,  // [128][512] bf16
    const float* __restrict__ lin_b, const float* __restrict__ conv_b,
    const float* __restrict__ curv, float* __restrict__ out) {
    __shared__ __align__(16) unsigned short As[3][RB * BK];    // 8 KB each
    __shared__ __align__(16) unsigned short Bs[3][RB * BK];    // 8 KB each
    int tid = threadIdx.x;
    int n0 = blockIdx.x * RB;
    int w = tid >> 6;        // wave 0..7
    int lane = tid & 63;
    int ml = lane & 15;
    int q = lane >> 4;
    int sr = tid >> 2;       // staging row 0..127 (1 load/lane per operand)
    int sj = tid & 3;        // staging chunk 0..3
    int sjg = sj ^ (sr & 3); // XOR-swizzled global chunk for this lane

    f32x4 acc[8];
    #pragma unroll
    for (int i = 0; i < 8; ++i) acc[i] = (f32x4){0.f, 0.f, 0.f, 0.f};

    // prologue: stage chunks 0 and 1 (2 loads each per thread)
    gload_lds16(A + (n0 + sr) * 512 + 0 * 32 + sjg * 8, &As[0][w * 512]);
    gload_lds16(Wt + sr * 512 + 0 * 32 + sjg * 8, &Bs[0][w * 512]);
    gload_lds16(A + (n0 + sr) * 512 + 1 * 32 + sjg * 8, &As[1][w * 512]);
    gload_lds16(Wt + sr * 512 + 1 * 32 + sjg * 8, &Bs[1][w * 512]);

    #pragma unroll
    for (int kk = 0; kk < 16; ++kk) {
        int cur = kk % 3;
        if (kk + 2 < 16) {
            int nb = (kk + 2) % 3;
            gload_lds16(A + (n0 + sr) * 512 + (kk + 2) * 32 + sjg * 8, &As[nb][w * 512]);
            gload_lds16(Wt + sr * 512 + (kk + 2) * 32 + sjg * 8, &Bs[nb][w * 512]);
        }
        // counted drain: stage(kk) retired; kk+1/kk+2 (4 loads) stay in flight
        if (kk < 14)       asm volatile("s_waitcnt vmcnt(4)" ::: "memory");
        else if (kk == 14) asm volatile("s_waitcnt vmcnt(2)" ::: "memory");
        else               asm volatile("s_waitcnt vmcnt(0)" ::: "memory");
        __builtin_amdgcn_s_barrier();   // raw: no vmcnt(0) drain
        __builtin_amdgcn_s_setprio(1);
        {
            int ca = (q ^ (ml & 3)) * 8;  // un-swizzle: row&3 == ml&3
            s16x8 a = *(const s16x8*)&As[cur][(w * 16 + ml) * BK + ca];
            #pragma unroll
            for (int ct = 0; ct < 8; ++ct) {
                s16x8 bb = *(const s16x8*)&Bs[cur][(ct * 16 + ml) * BK + ca];
                acc[ct] = __builtin_amdgcn_mfma_f32_16x16x32_bf16(a, bb, acc[ct], 0, 0, 0);
            }
        }
        __builtin_amdgcn_s_setprio(0);
        __builtin_amdgcn_s_barrier();   // all waves done reading buf[cur]
    }

    float c = fabsf(curv[0]);
    float sc = sqrtf(c);
    float cb[8], lb[8];
    #pragma unroll
    for (int ct = 0; ct < 8; ++ct) {
        cb[ct] = conv_b[ct * 16 + ml];
        lb[ct] = lin_b[ct * 16 + ml];
    }
    #pragma unroll
    for (int r = 0; r < 4; ++r) {
        int n = n0 + w * 16 + q * 4 + r;  // D-frag: row = quad*4 + reg, col = ml
        bool valid = (n < N_NODES);
        float dgf = 0.f;
        if (valid) dgf = (deg[n * CSTRIDE] > 0) ? 1.0f : 0.0f;
        float y[8];
        float ssq = 0.f;
        #pragma unroll
        for (int ct = 0; ct < 8; ++ct) {
            float v = acc[ct][r] + cb[ct] + dgf * lb[ct];
            y[ct] = v;
            ssq += v * v;
        }
        ssq += __shfl_xor(ssq, 1, 64);
        ssq += __shfl_xor(ssq, 2, 64);
        ssq += __shfl_xor(ssq, 4, 64);
        ssq += __shfl_xor(ssq, 8, 64);
        float un = fmaxf(sqrtf(ssq), 1e-15f);
        float z = sc * un;
        float os;
        if (z < 0.25f) {
            float z2 = z * z;
            os = 1.0f + z2 * (-0.33333333f + z2 * (0.13333333f - z2 * 0.053968254f));
        } else {
            os = tanhf(z) / z;
        }
        if (valid) {
            #pragma unroll
            for (int ct = 0; ct < 8; ++ct)
                out[n * DIM + ct * 16 + ml] = y[ct] * os;  // f32 output
        }
    }
}

extern "C" void kernel_launch(void* const* d_in, const int* in_sizes, int n_in,
                              void* d_out, int out_size, void* d_ws, size_t ws_size,
                              hipStream_t stream) {
    (void)in_sizes; (void)n_in; (void)out_size; (void)ws_size;
    const float* node   = (const float*)d_in[0];
    const float* h1     = (const float*)d_in[1];
    const float* h2     = (const float*)d_in[2];
    const float* h3     = (const float*)d_in[3];
    const float* lin_w  = (const float*)d_in[4];
    const float* lin_b  = (const float*)d_in[5];
    const float* conv_w = (const float*)d_in[6];
    const float* conv_b = (const float*)d_in[7];
    const float* curv   = (const float*)d_in[8];
    const int* esrc = (const int*)d_in[9];
    const int* edst = (const int*)d_in[10];
    float* out = (float*)d_out;

    // ws layout (bytes), total 76,931,072:
    //   [0, 51,200,000)           A        bf16 [50000][512]
    //   [51,200,000, 64,000,000)  node_t   bf16 [N][128]
    //   [64,000,000, 64,131,072)  Wt       bf16 [128][512]
    //   [64,131,072, 67,331,072)  cnt      i32 [N][16] (64B-padded counters)
    //   [67,331,072, 76,931,072)  slots    u16 [N][96] fixed-slot CSR
    char* ws = (char*)d_ws;
    unsigned short* A = (unsigned short*)ws;
    unsigned short* node_t = (unsigned short*)(ws + 51200000);
    unsigned short* Wt = (unsigned short*)(ws + 64000000);
    int* cnt = (int*)(ws + 64131072);
    unsigned short* slots = (unsigned short*)(ws + 67331072);

    (void)hipMemsetAsync(cnt, 0, N_NODES * CSTRIDE * sizeof(int), stream);
    hipLaunchKernelGGL(k_sb, dim3(SB_BLOCKS), dim3(256), 0, stream,
                       node, h1, h2, h3, lin_w, conv_w, curv, esrc, edst,
                       node_t, A, Wt, cnt, slots);
    hipLaunchKernelGGL(k_gather, dim3(3125), dim3(256), 0, stream,
                       slots, cnt, node_t, A);
    hipLaunchKernelGGL(k_gemm, dim3((N_NODES + RB - 1) / RB), dim3(512), 0, stream,
                       A, cnt, Wt, lin_b, conv_b, curv, out);
}

// Round 15
// 202.631 us; speedup vs baseline: 1.0242x; 1.0242x over previous
//
#include <hip/hip_runtime.h>
#include <hip/hip_bf16.h>

#define N_NODES 50000
#define DIM 128
#define N_EDGES 625000
#define EBLK 2442  // ceil(E/256) edge blocks, 1 edge/thread
#define SLOTS 96   // fixed CSR slots/node; deg ~ Binom(625k,1/50k): P(>96) ~ 1e-90
#define CSTRIDE 16 // cnt padded: 1 counter per 64B line (kills XCD line bouncing)

// fused setup+bucket grid: scale (25000) + pack (256) interleaved with bucket (2442)
#define SC_BLOCKS 25000           // 8 rows/block over 4N rows
#define PK_BLOCKS 256             // W-pack: 65536 elems
#define OT_BLOCKS (SC_BLOCKS + PK_BLOCKS)   // 25256 "other" blocks
#define IL_SPAN (EBLK * 11)       // 26862: interleave span (1 bucket per 11)
#define SB_BLOCKS (OT_BLOCKS + EBLK)        // 27698 total

typedef float f32x4 __attribute__((ext_vector_type(4)));
typedef short s16x8 __attribute__((ext_vector_type(8)));

__device__ __forceinline__ unsigned short f2bf(float f) {
    unsigned u = __builtin_bit_cast(unsigned, f);
    unsigned r = (u + 0x7fffu + ((u >> 16) & 1u)) >> 16;  // RNE
    return (unsigned short)r;
}
__device__ __forceinline__ unsigned cvtpk_bf16(float lo, float hi) {
    // v_cvt_pk_bf16_f32 via intrinsic; union pun (bit_cast rejects bf162)
    union { __hip_bfloat162 h; unsigned u; } cv;
    cv.h = __float22bfloat162_rn(make_float2(lo, hi));
    return cv.u;
}
__device__ __forceinline__ float lo_bf(unsigned u) {
    return __builtin_bit_cast(float, u << 16);
}
__device__ __forceinline__ float hi_bf(unsigned u) {
    return __builtin_bit_cast(float, u & 0xffff0000u);
}

// async global->LDS, 16 B per lane; lds dest = uniform base + lane*16 (m104)
__device__ __forceinline__ void gload_lds16(const unsigned short* g, unsigned short* l) {
    __builtin_amdgcn_global_load_lds(
        (const __attribute__((address_space(1))) void*)g,
        (__attribute__((address_space(3))) void*)l, 16, 0, 0);
}

// logmap0 scale factor for one row given sum-of-squares reduced across group
__device__ __forceinline__ float logmap_scale(float ss, float sc) {
    float xn = fmaxf(sqrtf(ss), 1e-15f);
    float arg = fminf(sc * xn, 1.0f - 1e-5f);
    // s = artanh(arg)/(sc*xn); for arg<0.25 the clip is inactive so the
    // division cancels: artanh(z)/z = 1 + z^2/3 + z^4/5 + z^6/7 (rel err ~2e-6)
    if (arg < 0.25f) {
        float z2 = arg * arg;
        return 1.0f + z2 * (0.33333333f + z2 * (0.2f + z2 * 0.14285715f));
    }
    float at = 0.5f * log1pf(2.0f * arg / (1.0f - arg));
    return at / (sc * xn);
}

// ---- K1: fused setup + pack + INTERLEAVED bucket (R11-measured: 50us,
// bucket hides under setup; serial tail-fusion was 63) -- FROZEN ----
__global__ __launch_bounds__(256) void k_sb(
    const float* __restrict__ node, const float* __restrict__ h1,
    const float* __restrict__ h2, const float* __restrict__ h3,
    const float* __restrict__ lin_w, const float* __restrict__ conv_w,
    const float* __restrict__ curv,
    const int* __restrict__ esrc, const int* __restrict__ edst,
    unsigned short* __restrict__ node_t, unsigned short* __restrict__ A,
    unsigned short* __restrict__ Wt, int* __restrict__ cnt,
    unsigned short* __restrict__ slots) {
    int b = blockIdx.x;
    int tid = threadIdx.x;
    int ot;
    if (b < IL_SPAN) {
        int q = b / 11;
        int r = b - q * 11;
        if (r == 5) {  // ---- bucket block: 1 edge/thread, padded counters ----
            int e = q * 256 + tid;
            if (e < N_EDGES) {
                int d = edst[e];
                int pos = __hip_atomic_fetch_add(&cnt[d * CSTRIDE], 1,
                                                 __ATOMIC_RELAXED,
                                                 __HIP_MEMORY_SCOPE_AGENT);
                if (pos < SLOTS) slots[d * SLOTS + pos] = (unsigned short)esrc[e];
            }
            return;
        }
        ot = q * 10 + (r < 5 ? r : r - 1);
    } else {
        ot = 24420 + (b - IL_SPAN);
    }
    if (ot < SC_BLOCKS) {
        // ---- scale: 32 lanes/row, one float4/lane = dense 1KB loads ----
        int row = ot * 8 + (tid >> 5);  // [0, 4N); row uniform per 32-lane group
        int g = tid & 31;               // float4 index within the 128-float row
        int a = row / N_NODES;
        int n = row - a * N_NODES;
        const float* src = (a == 0) ? node : (a == 1) ? h1 : (a == 2) ? h2 : h3;
        float4 x = ((const float4*)&src[n * DIM])[g];
        float ss = x.x * x.x + x.y * x.y + x.z * x.z + x.w * x.w;
        ss += __shfl_xor(ss, 1, 64);
        ss += __shfl_xor(ss, 2, 64);
        ss += __shfl_xor(ss, 4, 64);
        ss += __shfl_xor(ss, 8, 64);
        ss += __shfl_xor(ss, 16, 64);  // 32-lane group reduction
        float c = fabsf(curv[0]);
        float s = logmap_scale(ss, sqrtf(c));
        uint2 ov;
        ov.x = cvtpk_bf16(x.x * s, x.y * s);
        ov.y = cvtpk_bf16(x.z * s, x.w * s);
        if (a == 0) {  // uniform per 32-lane group
            *(uint2*)&node_t[n * DIM + g * 4] = ov;
        } else {
            *(uint2*)&A[n * 512 + a * 128 + g * 4] = ov;
        }
    } else {
        // ---- pack Wt ----
        int idx = (ot - SC_BLOCKS) * 256 + tid;  // 65536
        int o = idx >> 9;
        int k = idx & 511;
        float v;
        if (k < 128) {
            v = lin_w[o * 128 + k];
        } else {
            int kk = (k - 128) >> 7;
            int i = (k - 128) & 127;
            v = conv_w[o * 384 + i * 3 + kk];
        }
        Wt[idx] = f2bf(v);
    }
}

// ---- K2: gather: A[n][0:128] = bf16(avg of node_t rows in slot list n) ----
// 16 lanes/node, uint4 per lane; inner loop restructured to a SINGLE masked
// batch of 16 in-flight loads per 16-slot chunk (was 2x8 sequential) -- 2x
// the outstanding loads per dependency chain for the typical deg~12.5 node.
__global__ __launch_bounds__(256) void k_gather(
    const unsigned short* __restrict__ slots, const int* __restrict__ cnt,
    const unsigned short* __restrict__ node_t, unsigned short* __restrict__ A) {
    int n = blockIdx.x * 16 + (threadIdx.x >> 4);  // 16 nodes/block
    int lane = threadIdx.x & 15;                   // cols [8*lane, 8*lane+8)
    int ctrue = cnt[n * CSTRIDE];
    int c = ctrue < SLOTS ? ctrue : SLOTS;
    const unsigned short* row = &slots[n * SLOTS];
    float p0 = 0.f, p1 = 0.f, p2 = 0.f, p3 = 0.f;   // even-slot partials
    float p4 = 0.f, p5 = 0.f, p6 = 0.f, p7 = 0.f;
    float q0 = 0.f, q1 = 0.f, q2 = 0.f, q3 = 0.f;   // odd-slot partials
    float q4 = 0.f, q5 = 0.f, q6 = 0.f, q7 = 0.f;
    for (int base = 0; base < c; base += 16) {
        int rem = c - base;
        int m = rem < 16 ? rem : 16;
        int my = (int)row[base + (lane < m ? lane : m - 1)];
        int s[16];
        #pragma unroll
        for (int i = 0; i < 16; ++i)
            s[i] = __shfl(my, (i < m ? i : m - 1), 16);
        uint4 u[16];
        #pragma unroll
        for (int i = 0; i < 16; ++i)
            u[i] = *(const uint4*)&node_t[s[i] * DIM + lane * 8];
        #pragma unroll
        for (int i = 0; i < 16; ++i) {
            bool on = (i < m);
            if (i & 1) {
                if (on) {
                    q0 += lo_bf(u[i].x); q1 += hi_bf(u[i].x);
                    q2 += lo_bf(u[i].y); q3 += hi_bf(u[i].y);
                    q4 += lo_bf(u[i].z); q5 += hi_bf(u[i].z);
                    q6 += lo_bf(u[i].w); q7 += hi_bf(u[i].w);
                }
            } else {
                if (on) {
                    p0 += lo_bf(u[i].x); p1 += hi_bf(u[i].x);
                    p2 += lo_bf(u[i].y); p3 += hi_bf(u[i].y);
                    p4 += lo_bf(u[i].z); p5 += hi_bf(u[i].z);
                    p6 += lo_bf(u[i].w); p7 += hi_bf(u[i].w);
                }
            }
        }
    }
    float inv = (ctrue > 0) ? 1.0f / (float)ctrue : 0.0f;
    uint4 ov;
    ov.x = cvtpk_bf16((p0 + q0) * inv, (p1 + q1) * inv);
    ov.y = cvtpk_bf16((p2 + q2) * inv, (p3 + q3) * inv);
    ov.z = cvtpk_bf16((p4 + q4) * inv, (p5 + q5) * inv);
    ov.w = cvtpk_bf16((p6 + q6) * inv, (p7 + q7) * inv);
    *(uint4*)&A[n * 512 + lane * 8] = ov;
}

// ---- K3: [N x 512] @ [512 x 128] bf16 MFMA GEMM + expmap0 epilogue ----
// R12-EXACT form (best measured: 202.2us total): RB=128, BK=64, 512T
// (8 waves, 16 rows/wave), 64KB LDS, 2-buffer __syncthreads pipeline.
// BK=32 full-occupancy (R13: +2.8) and T4 counted-vmcnt (R14: +5.3) both
// regressed -- this structure is gemm's measured optimum.
#define RB 128
#define BK 64
__global__ __launch_bounds__(512) void k_gemm(
    const unsigned short* __restrict__ A, const int* __restrict__ deg,  // deg stride CSTRIDE
    const unsigned short* __restrict__ Wt,  // [128][512] bf16
    const float* __restrict__ lin_b, const float* __restrict__ conv_b,
    const float* __restrict__ curv, float* __restrict__ out) {
    __shared__ __align__(16) unsigned short As[2][RB * BK];    // 16 KB each
    __shared__ __align__(16) unsigned short Bs[2][128 * BK];   // 16 KB each
    int tid = threadIdx.x;
    int n0 = blockIdx.x * RB;
    int w = tid >> 6;        // wave 0..7
    int lane = tid & 63;
    int ml = lane & 15;
    int q = lane >> 4;
    int lr = lane >> 3;      // row-within-8 for staging
    int lj = lane & 7;       // 16B-chunk-within-row for staging

    f32x4 acc[8];
    #pragma unroll
    for (int i = 0; i < 8; ++i) acc[i] = (f32x4){0.f, 0.f, 0.f, 0.f};

    // prologue: stage chunk 0 into buffer 0 (A: 16x1KB, B: 16x1KB; 2/wave)
    #pragma unroll
    for (int t = 0; t < 2; ++t) {
        int m = t * 8 + w;
        int r = m * 8 + lr;
        int jg = lj ^ (r & 7);
        gload_lds16(A + (n0 + r) * 512 + jg * 8, &As[0][m * 512]);
    }
    #pragma unroll
    for (int t = 0; t < 2; ++t) {
        int m = t * 8 + w;
        int r = m * 8 + lr;
        int jg = lj ^ (r & 7);
        gload_lds16(Wt + r * 512 + jg * 8, &Bs[0][m * 512]);
    }

    #pragma unroll
    for (int kk = 0; kk < 8; ++kk) {
        int cur = kk & 1;
        __syncthreads();  // drains stage-kk loads; all waves done with other buf
        if (kk < 7) {
            int nb = cur ^ 1;
            #pragma unroll
            for (int t = 0; t < 2; ++t) {
                int m = t * 8 + w;
                int r = m * 8 + lr;
                int jg = lj ^ (r & 7);
                gload_lds16(A + (n0 + r) * 512 + (kk + 1) * 64 + jg * 8, &As[nb][m * 512]);
            }
            #pragma unroll
            for (int t = 0; t < 2; ++t) {
                int m = t * 8 + w;
                int r = m * 8 + lr;
                int jg = lj ^ (r & 7);
                gload_lds16(Wt + r * 512 + (kk + 1) * 64 + jg * 8, &Bs[nb][m * 512]);
            }
        }
        __builtin_amdgcn_s_setprio(1);
        #pragma unroll
        for (int ks = 0; ks < 2; ++ks) {
            int ca = ((ks * 4 + q) ^ (ml & 7)) * 8;
            s16x8 a = *(const s16x8*)&As[cur][(w * 16 + ml) * BK + ca];
            #pragma unroll
            for (int ct = 0; ct < 8; ++ct) {
                s16x8 bb = *(const s16x8*)&Bs[cur][(ct * 16 + ml) * BK + ca];
                acc[ct] = __builtin_amdgcn_mfma_f32_16x16x32_bf16(a, bb, acc[ct], 0, 0, 0);
            }
        }
        __builtin_amdgcn_s_setprio(0);
    }

    float c = fabsf(curv[0]);
    float sc = sqrtf(c);
    float cb[8], lb[8];
    #pragma unroll
    for (int ct = 0; ct < 8; ++ct) {
        cb[ct] = conv_b[ct * 16 + ml];
        lb[ct] = lin_b[ct * 16 + ml];
    }
    #pragma unroll
    for (int r = 0; r < 4; ++r) {
        int n = n0 + w * 16 + q * 4 + r;  // D-frag: row = quad*4 + reg, col = ml
        bool valid = (n < N_NODES);
        float dgf = 0.f;
        if (valid) dgf = (deg[n * CSTRIDE] > 0) ? 1.0f : 0.0f;
        float y[8];
        float ssq = 0.f;
        #pragma unroll
        for (int ct = 0; ct < 8; ++ct) {
            float v = acc[ct][r] + cb[ct] + dgf * lb[ct];
            y[ct] = v;
            ssq += v * v;
        }
        ssq += __shfl_xor(ssq, 1, 64);
        ssq += __shfl_xor(ssq, 2, 64);
        ssq += __shfl_xor(ssq, 4, 64);
        ssq += __shfl_xor(ssq, 8, 64);
        float un = fmaxf(sqrtf(ssq), 1e-15f);
        float z = sc * un;
        float os;
        if (z < 0.25f) {
            float z2 = z * z;
            os = 1.0f + z2 * (-0.33333333f + z2 * (0.13333333f - z2 * 0.053968254f));
        } else {
            os = tanhf(z) / z;
        }
        if (valid) {
            #pragma unroll
            for (int ct = 0; ct < 8; ++ct)
                out[n * DIM + ct * 16 + ml] = y[ct] * os;  // f32 output
        }
    }
}

extern "C" void kernel_launch(void* const* d_in, const int* in_sizes, int n_in,
                              void* d_out, int out_size, void* d_ws, size_t ws_size,
                              hipStream_t stream) {
    (void)in_sizes; (void)n_in; (void)out_size; (void)ws_size;
    const float* node   = (const float*)d_in[0];
    const float* h1     = (const float*)d_in[1];
    const float* h2     = (const float*)d_in[2];
    const float* h3     = (const float*)d_in[3];
    const float* lin_w  = (const float*)d_in[4];
    const float* lin_b  = (const float*)d_in[5];
    const float* conv_w = (const float*)d_in[6];
    const float* conv_b = (const float*)d_in[7];
    const float* curv   = (const float*)d_in[8];
    const int* esrc = (const int*)d_in[9];
    const int* edst = (const int*)d_in[10];
    float* out = (float*)d_out;

    // ws layout (bytes), total 76,931,072:
    //   [0, 51,200,000)           A        bf16 [50000][512]
    //   [51,200,000, 64,000,000)  node_t   bf16 [N][128]
    //   [64,000,000, 64,131,072)  Wt       bf16 [128][512]
    //   [64,131,072, 67,331,072)  cnt      i32 [N][16] (64B-padded counters)
    //   [67,331,072, 76,931,072)  slots    u16 [N][96] fixed-slot CSR
    char* ws = (char*)d_ws;
    unsigned short* A = (unsigned short*)ws;
    unsigned short* node_t = (unsigned short*)(ws + 51200000);
    unsigned short* Wt = (unsigned short*)(ws + 64000000);
    int* cnt = (int*)(ws + 64131072);
    unsigned short* slots = (unsigned short*)(ws + 67331072);

    (void)hipMemsetAsync(cnt, 0, N_NODES * CSTRIDE * sizeof(int), stream);
    hipLaunchKernelGGL(k_sb, dim3(SB_BLOCKS), dim3(256), 0, stream,
                       node, h1, h2, h3, lin_w, conv_w, curv, esrc, edst,
                       node_t, A, Wt, cnt, slots);
    hipLaunchKernelGGL(k_gather, dim3(3125), dim3(256), 0, stream,
                       slots, cnt, node_t, A);
    hipLaunchKernelGGL(k_gemm, dim3((N_NODES + RB - 1) / RB), dim3(512), 0, stream,
                       A, cnt, Wt, lin_b, conv_b, curv, out);
}